// Round 13
// baseline (168.170 us; speedup 1.0000x reference)
//
#include <hip/hip_runtime.h>

// B=131072 points (D=16 fp32), K=256 centers. Out (fp32): [B] argmin idx ++ [B,16] offsets.
//
// ROUND-13 = MEASUREMENT + FIX round.
// (1) MEASUREMENT: the k-scan repeats 8x (#pragma unroll 1; best/bi carry
//     across repeats, strict < => repeats 2..8 change nothing; table too big
//     to CSE from registers, so HW re-executes). Kernel becomes big enough to
//     enter rocprof's top-5 over the ~41us harness fills => first direct
//     VALUBusy/Occupancy/FETCH evidence for the hot loop since r1.
//     Per-scan cost = (kernel_dur - ~4us fixed)/8.
// (2) FIX under test: DIM-PACKED v2f k-loop. acc={sum_even+c2, sum_odd};
//     center pair {c_2j,c_2j+1} = consecutive SGPRs straight out of
//     s_load_dwordx16 (no splat v_movs, no prep table, K$ stays 16KB).
//     12 VALU ops/pt/center vs r5's ~27-with-splats. VALU floor ~5.1us.
// Summation reorder is argmin-safe (r1-r12 already reordered vs np ref,
// absmax 0; random-normal data has no fp32-near-ties across 131072 pts).
//
// Block = 256 thr = 4 waves, 128 pts (2/lane, chains ya/yb). Wave w scans
// centers [64w,64w+64); k wave-uniform -> s_load. Strict < + ascending
// k/chunk => lowest-k ties (jnp.argmin). Epilogue: r11 LDS center gather.

constexpr int Bn = 131072;
constexpr int Kn = 256;
constexpr int Dn = 16;
constexpr int PTS = 128;      // points per block (2 per lane)
constexpr int NW = 4;         // waves per block == K chunks
constexpr int KC = Kn / NW;   // 64 centers per wave
constexpr int REPEAT = 8;     // measurement amplification (see header)

typedef float v2f __attribute__((ext_vector_type(2)));

__global__ __launch_bounds__(256, 8) void kmeans_kernel(
    const float* __restrict__ traj, const float* __restrict__ centers,
    float* __restrict__ out) {
  __shared__ float c2s[Kn];
  __shared__ float4 cs4[Kn][4];     // centers copy for the epilogue gather (16KB)
  __shared__ float sbest[NW * PTS];
  __shared__ int sbi[NW * PTS];
  __shared__ int swin[PTS];

  const int t = threadIdx.x;
  const int blk = blockIdx.x;

  // ---- Stage 1: thread t loads center row t, computes c2, stages row in LDS.
  {
    const float4* cp = reinterpret_cast<const float4*>(centers + t * Dn);
    float4 a = cp[0], b = cp[1], c = cp[2], d = cp[3];
    float s = 0.0f;
    s = fmaf(a.x, a.x, s); s = fmaf(a.y, a.y, s);
    s = fmaf(a.z, a.z, s); s = fmaf(a.w, a.w, s);
    s = fmaf(b.x, b.x, s); s = fmaf(b.y, b.y, s);
    s = fmaf(b.z, b.z, s); s = fmaf(b.w, b.w, s);
    s = fmaf(c.x, c.x, s); s = fmaf(c.y, c.y, s);
    s = fmaf(c.z, c.z, s); s = fmaf(c.w, c.w, s);
    s = fmaf(d.x, d.x, s); s = fmaf(d.y, d.y, s);
    s = fmaf(d.z, d.z, s); s = fmaf(d.w, d.w, s);
    c2s[t] = s;
    cs4[t][0] = a; cs4[t][1] = b; cs4[t][2] = c; cs4[t][3] = d;
  }
  __syncthreads();

  const int w = __builtin_amdgcn_readfirstlane(t >> 6);  // wave id (SGPR)
  const int l = t & 63;                                  // lane
  const int p0 = blk * PTS + l;        // this lane's point 0
  const int p1 = p0 + 64;              // this lane's point 1

  // ---- DIM-packed y = -2*x: ya[j] = {x_2j, x_2j+1} of p0, yb likewise p1.
  v2f ya[8], yb[8];
  {
    const v2f* xa = reinterpret_cast<const v2f*>(traj + (size_t)p0 * Dn);
    const v2f* xb = reinterpret_cast<const v2f*>(traj + (size_t)p1 * Dn);
#pragma unroll
    for (int j = 0; j < 8; ++j) {
      v2f a = xa[j], b = xb[j];
      ya[j] = (v2f){-2.0f * a.x, -2.0f * a.y};
      yb[j] = (v2f){-2.0f * b.x, -2.0f * b.y};
    }
  }

  float best0 = __builtin_inff(), best1 = __builtin_inff();
  int bi0 = 0, bi1 = 0;
  const int k0 = w * KC;

#pragma unroll 1
  for (int rep = 0; rep < REPEAT; ++rep) {
#pragma unroll 4
    for (int kk = 0; kk < KC; ++kk) {
      const int k = k0 + kk;
      // wave-uniform row -> s_load_dwordx16; pairs {c_2j,c_2j+1} are
      // consecutive SGPRs (even-aligned), direct VOP3P scalar operands.
      const v2f* rp = reinterpret_cast<const v2f*>(centers + k * Dn);
      const float c2k = c2s[k];
      v2f aa = (v2f){c2k, 0.0f};
      v2f ab = (v2f){c2k, 0.0f};
#pragma unroll
      for (int j = 0; j < 8; ++j) {
        const v2f c = rp[j];
        aa = ya[j] * c + aa;             // v_pk_fma_f32, no splat
        ab = yb[j] * c + ab;
      }
      const float s0 = aa.x + aa.y;      // horizontal: even+odd partials
      const float s1 = ab.x + ab.y;
      if (s0 < best0) { best0 = s0; bi0 = k; }  // strict <: lowest-k ties
      if (s1 < best1) { best1 = s1; bi1 = k; }
    }
  }

  sbest[w * PTS + l] = best0;
  sbi[w * PTS + l] = bi0;
  sbest[w * PTS + 64 + l] = best1;
  sbi[w * PTS + 64 + l] = bi1;
  __syncthreads();

  // ---- Cross-wave reduction: threads 0..127, one per point. Ascending chunk
  // order + strict < keeps the lowest-k winner on exact ties.
  if (t < PTS) {
    float b0 = sbest[t];
    int i0 = sbi[t];
#pragma unroll
    for (int ww = 1; ww < NW; ++ww) {
      float b1 = sbest[ww * PTS + t];
      int i1 = sbi[ww * PTS + t];
      if (b1 < b0) { b0 = b1; i0 = i1; }
    }
    swin[t] = i0;
    out[blk * PTS + t] = (float)i0;  // idx output (fp32 buffer), coalesced
  }
  __syncthreads();

  // ---- Coalesced offset stores: 128 points x 4 quarters = 512 float4 ops.
#pragma unroll
  for (int it = 0; it < 2; ++it) {
    const int id = it * 256 + t;
    const int pb = id >> 2, q = id & 3;
    const int pt = blk * PTS + pb;
    const int win = swin[pb];
    float4 xv = reinterpret_cast<const float4*>(traj + (size_t)pt * Dn)[q];  // L1-hot
    float4 cv = cs4[win][q];                                                 // LDS gather
    float4 o = make_float4(xv.x - cv.x, xv.y - cv.y, xv.z - cv.z, xv.w - cv.w);
    reinterpret_cast<float4*>(out + Bn)[(size_t)pt * 4 + q] = o;
  }
}

extern "C" void kernel_launch(void* const* d_in, const int* in_sizes, int n_in,
                              void* d_out, int out_size, void* d_ws, size_t ws_size,
                              hipStream_t stream) {
  (void)in_sizes; (void)n_in; (void)out_size; (void)d_ws; (void)ws_size;
  const float* traj = (const float*)d_in[0];     // [131072, 16]
  const float* centers = (const float*)d_in[1];  // [256, 16]
  float* out = (float*)d_out;                    // [131072] idx ++ [131072*16] offsets
  kmeans_kernel<<<Bn / PTS, 256, 0, stream>>>(traj, centers, out);
}

// Round 14
// 73.660 us; speedup vs baseline: 2.2831x; 2.2831x over previous
//
#include <hip/hip_runtime.h>

// B=131072 points (D=16 fp32), K=256 centers. Out (fp32): [B] argmin idx ++ [B,16] offsets.
//
// Round-14: HARVEST. r13's amplified measurement (first direct counters:
// VALUBusy 79%, scan ~16us/scan, VALU-active 12.6us vs 5.1us packed-ideal)
// showed the dim-packed v2f loop suffers ~2.5x VALU bloat: LLVM won't feed
// v_pk_fma_f32 from SGPR pairs and inserts v_mov copies. The scalar path is
// PROVEN clean (r1: v_fmac_f32 with direct SGPR operand, VGPR=20, no movs):
// per k-iter (2 pts/lane) 32 fma + 6 sel = 38 VALU instr -> scan ~8.1us.
// REPEAT back to 1. Kernel ~13us expected.
//
// Block = 256 thr = 4 waves, 128 pts (2/lane, independent fma chains for
// ILP). Wave w scans centers [64w,64w+64); k wave-uniform -> s_load row.
// score = c2[k] + sum_d x_d*(-2 c_d)... expressed as c2s[k] then d-ascending
// fmaf(y[d], cr[d], acc) with y=-2x — identical fp32 op order to r1/r5/r11
// (absmax 0). Strict < + ascending k/chunk => lowest-k ties (jnp.argmin).
// Epilogue: r11 LDS center staging + gather (small verified win).

constexpr int Bn = 131072;
constexpr int Kn = 256;
constexpr int Dn = 16;
constexpr int PTS = 128;      // points per block (2 per lane)
constexpr int NW = 4;         // waves per block == K chunks
constexpr int KC = Kn / NW;   // 64 centers per wave

__global__ __launch_bounds__(256, 8) void kmeans_kernel(
    const float* __restrict__ traj, const float* __restrict__ centers,
    float* __restrict__ out) {
  __shared__ float c2s[Kn];
  __shared__ float4 cs4[Kn][4];     // centers copy for the epilogue gather (16KB)
  __shared__ float sbest[NW * PTS];
  __shared__ int sbi[NW * PTS];
  __shared__ int swin[PTS];

  const int t = threadIdx.x;
  const int blk = blockIdx.x;

  // ---- Stage 1: thread t loads center row t, computes c2, stages row in LDS.
  {
    const float4* cp = reinterpret_cast<const float4*>(centers + t * Dn);
    float4 a = cp[0], b = cp[1], c = cp[2], d = cp[3];
    float s = 0.0f;
    s = fmaf(a.x, a.x, s); s = fmaf(a.y, a.y, s);
    s = fmaf(a.z, a.z, s); s = fmaf(a.w, a.w, s);
    s = fmaf(b.x, b.x, s); s = fmaf(b.y, b.y, s);
    s = fmaf(b.z, b.z, s); s = fmaf(b.w, b.w, s);
    s = fmaf(c.x, c.x, s); s = fmaf(c.y, c.y, s);
    s = fmaf(c.z, c.z, s); s = fmaf(c.w, c.w, s);
    s = fmaf(d.x, d.x, s); s = fmaf(d.y, d.y, s);
    s = fmaf(d.z, d.z, s); s = fmaf(d.w, d.w, s);
    c2s[t] = s;
    cs4[t][0] = a; cs4[t][1] = b; cs4[t][2] = c; cs4[t][3] = d;
  }
  __syncthreads();

  const int w = __builtin_amdgcn_readfirstlane(t >> 6);  // wave id (SGPR)
  const int l = t & 63;                                  // lane
  const int p0 = blk * PTS + l;        // this lane's point 0
  const int p1 = p0 + 64;              // this lane's point 1

  // ---- y = -2*x for both points (scalar registers; clean VGPR layout).
  float y0[Dn], y1[Dn];
  {
    const float4* xa = reinterpret_cast<const float4*>(traj + (size_t)p0 * Dn);
    const float4* xb = reinterpret_cast<const float4*>(traj + (size_t)p1 * Dn);
#pragma unroll
    for (int q = 0; q < 4; ++q) {
      float4 a = xa[q], b = xb[q];
      y0[q * 4 + 0] = -2.0f * a.x;  y1[q * 4 + 0] = -2.0f * b.x;
      y0[q * 4 + 1] = -2.0f * a.y;  y1[q * 4 + 1] = -2.0f * b.y;
      y0[q * 4 + 2] = -2.0f * a.z;  y1[q * 4 + 2] = -2.0f * b.z;
      y0[q * 4 + 3] = -2.0f * a.w;  y1[q * 4 + 3] = -2.0f * b.w;
    }
  }

  float best0 = __builtin_inff(), best1 = __builtin_inff();
  int bi0 = 0, bi1 = 0;
  const int k0 = w * KC;
#pragma unroll 4
  for (int kk = 0; kk < KC; ++kk) {
    const int k = k0 + kk;
    const float* cr = centers + k * Dn;  // wave-uniform -> s_load_dwordx16
    const float c2k = c2s[k];
    float a0 = c2k, a1 = c2k;            // two independent scalar fma chains
#pragma unroll
    for (int d = 0; d < Dn; ++d) {
      const float c = cr[d];             // SGPR; direct v_fmac operand
      a0 = fmaf(y0[d], c, a0);
      a1 = fmaf(y1[d], c, a1);
    }
    if (a0 < best0) { best0 = a0; bi0 = k; }  // strict <: lowest-k ties
    if (a1 < best1) { best1 = a1; bi1 = k; }
  }
  sbest[w * PTS + l] = best0;
  sbi[w * PTS + l] = bi0;
  sbest[w * PTS + 64 + l] = best1;
  sbi[w * PTS + 64 + l] = bi1;
  __syncthreads();

  // ---- Cross-wave reduction: threads 0..127, one per point. Ascending chunk
  // order + strict < keeps the lowest-k winner on exact ties.
  if (t < PTS) {
    float b0 = sbest[t];
    int i0 = sbi[t];
#pragma unroll
    for (int ww = 1; ww < NW; ++ww) {
      float b1 = sbest[ww * PTS + t];
      int i1 = sbi[ww * PTS + t];
      if (b1 < b0) { b0 = b1; i0 = i1; }
    }
    swin[t] = i0;
    out[blk * PTS + t] = (float)i0;  // idx output (fp32 buffer), coalesced
  }
  __syncthreads();

  // ---- Coalesced offset stores: 128 points x 4 quarters = 512 float4 ops.
#pragma unroll
  for (int it = 0; it < 2; ++it) {
    const int id = it * 256 + t;
    const int pb = id >> 2, q = id & 3;
    const int pt = blk * PTS + pb;
    const int win = swin[pb];
    float4 xv = reinterpret_cast<const float4*>(traj + (size_t)pt * Dn)[q];  // L1-hot
    float4 cv = cs4[win][q];                                                 // LDS gather
    float4 o = make_float4(xv.x - cv.x, xv.y - cv.y, xv.z - cv.z, xv.w - cv.w);
    reinterpret_cast<float4*>(out + Bn)[(size_t)pt * 4 + q] = o;
  }
}

extern "C" void kernel_launch(void* const* d_in, const int* in_sizes, int n_in,
                              void* d_out, int out_size, void* d_ws, size_t ws_size,
                              hipStream_t stream) {
  (void)in_sizes; (void)n_in; (void)out_size; (void)d_ws; (void)ws_size;
  const float* traj = (const float*)d_in[0];     // [131072, 16]
  const float* centers = (const float*)d_in[1];  // [256, 16]
  float* out = (float*)d_out;                    // [131072] idx ++ [131072*16] offsets
  kmeans_kernel<<<Bn / PTS, 256, 0, stream>>>(traj, centers, out);
}